// Round 1
// baseline (1251.275 us; speedup 1.0000x reference)
//
#include <hip/hip_runtime.h>
#include <math.h>

// CausalAttention: B=4, S=4096, DIN=DOUT=768, fp32 in/out, bf16 MFMA compute.
// ws layout: [0,256) atomic counter | xb bf16 | q bf16 (pre-scaled) | k bf16 |
//            vT bf16 [b][d][s] | Wt bf16 (3x transposed W)

typedef unsigned short u16;
typedef unsigned int u32;
typedef __attribute__((ext_vector_type(8))) __bf16 bf8;
typedef __attribute__((ext_vector_type(4))) float f32x4;

struct __align__(8) U4 { u16 x, y, z, w; };

#define LOG2E 1.4426950408889634f
#define QSCALE 0.03608439182435161f   // 1/sqrt(768)

__device__ __forceinline__ u16 f2bf(float f) {
  u32 u = __builtin_bit_cast(u32, f);
  u += 0x7FFFu + ((u >> 16) & 1u);      // RNE
  return (u16)(u >> 16);
}
__device__ __forceinline__ f32x4 mfma16(bf8 a, bf8 b, f32x4 c) {
  return __builtin_amdgcn_mfma_f32_16x16x32_bf16(a, b, c, 0, 0, 0);
}
__device__ __forceinline__ void stage16(const void* g, void* l) {
  __builtin_amdgcn_global_load_lds((const __attribute__((address_space(1))) void*)g,
                                   (__attribute__((address_space(3))) void*)l, 16, 0, 0);
}
// XOR swizzle, involution: key from bits >=7, modifies bits 4-6 (16B granules)
__device__ __forceinline__ u32 swz7(u32 off) { return off ^ (((off >> 7) & 7u) << 4); }

// ---------------- convert x (fp32 -> bf16), vectorized ----------------
__global__ void cvt_x_kernel(const float* __restrict__ x, u16* __restrict__ xb) {
  int i = blockIdx.x * 256 + threadIdx.x;          // float4 index, exact grid
  float4 v = ((const float4*)x)[i];
  U4 o; o.x = f2bf(v.x); o.y = f2bf(v.y); o.z = f2bf(v.z); o.w = f2bf(v.w);
  ((U4*)xb)[i] = o;
}

// ---------------- convert + transpose W: Wt[z][n][k] = bf16(W_z[k][n]) ----------------
__global__ void cvt_w_kernel(const float* __restrict__ Wq, const float* __restrict__ Wk,
                             const float* __restrict__ Wv, u16* __restrict__ wt) {
  __shared__ float tile[32][33];
  int z = blockIdx.z;
  const float* W = (z == 0) ? Wq : ((z == 1) ? Wk : Wv);
  u16* o = wt + (size_t)z * 589824;
  int n0 = blockIdx.x * 32, k0 = blockIdx.y * 32;
  int c = threadIdx.x & 31, r0 = threadIdx.x >> 5;   // 8 rows/pass
#pragma unroll
  for (int p = 0; p < 4; p++) tile[r0 + p * 8][c] = W[(size_t)(k0 + r0 + p * 8) * 768 + n0 + c];
  __syncthreads();
#pragma unroll
  for (int p = 0; p < 4; p++) o[(size_t)(n0 + r0 + p * 8) * 768 + k0 + c] = f2bf(tile[c][r0 + p * 8]);
}

// ---------------- QKV GEMM: C[16384x768] = xb * W_z, 128x128 tile, BK=64 ----------------
// z=0 -> q (scaled), z=1 -> k, z=2 -> v transposed [b][d][s]
__global__ __launch_bounds__(256) void gemm_qkv_kernel(
    const u16* __restrict__ xb, const u16* __restrict__ wt,
    u16* __restrict__ qo, u16* __restrict__ ko, u16* __restrict__ vT) {
  __shared__ char lA[16384];
  __shared__ char lB[16384];
  const int tid = threadIdx.x;
  const int lane = tid & 63, wvid = tid >> 6;
  const int wm = wvid >> 1, wn = wvid & 1;
  const int l15 = lane & 15, lg4 = lane >> 4;
  const int m0 = blockIdx.x * 128;
  const int n0 = blockIdx.y * 128;
  const int z = blockIdx.z;
  const u16* wz = wt + (size_t)z * 589824;

  f32x4 acc[4][4];
#pragma unroll
  for (int rt = 0; rt < 4; rt++)
#pragma unroll
    for (int nt = 0; nt < 4; nt++) acc[rt][nt] = f32x4{0.f, 0.f, 0.f, 0.f};

  for (int kt = 0; kt < 12; kt++) {
    // stage A and B tiles (16KB each) via global_load_lds, source-swizzled
#pragma unroll
    for (int i = 0; i < 4; i++) {
      u32 o = (u32)i * 4096u + (u32)wvid * 1024u + (u32)lane * 16u;
      u32 lg = swz7(o);
      u32 row = lg >> 7, kbyt = lg & 127u;
      stage16((const char*)xb + ((size_t)(m0 + row) * 1536 + (size_t)kt * 128 + kbyt),
              lA + (size_t)i * 4096 + (size_t)wvid * 1024);
      stage16((const char*)wz + ((size_t)(n0 + row) * 1536 + (size_t)kt * 128 + kbyt),
              lB + (size_t)i * 4096 + (size_t)wvid * 1024);
    }
    __syncthreads();
#pragma unroll
    for (int kk = 0; kk < 2; kk++) {
      bf8 af[4], bfr[4];
#pragma unroll
      for (int rt = 0; rt < 4; rt++) {
        u32 off = (u32)(wm * 64 + rt * 16 + l15) * 128u + (u32)kk * 64u + (u32)lg4 * 16u;
        af[rt] = *(const bf8*)(const void*)(lA + swz7(off));
      }
#pragma unroll
      for (int nt = 0; nt < 4; nt++) {
        u32 off = (u32)(wn * 64 + nt * 16 + l15) * 128u + (u32)kk * 64u + (u32)lg4 * 16u;
        bfr[nt] = *(const bf8*)(const void*)(lB + swz7(off));
      }
#pragma unroll
      for (int rt = 0; rt < 4; rt++)
#pragma unroll
        for (int nt = 0; nt < 4; nt++) acc[rt][nt] = mfma16(af[rt], bfr[nt], acc[rt][nt]);
    }
    __syncthreads();
  }
  // epilogue
  if (z == 2) {
#pragma unroll
    for (int rt = 0; rt < 4; rt++) {
      int m = m0 + wm * 64 + rt * 16 + lg4 * 4;   // first of 4 consecutive rows
      int batch = m >> 12;
      int s = m & 4095;
#pragma unroll
      for (int nt = 0; nt < 4; nt++) {
        int col = n0 + wn * 64 + nt * 16 + l15;
        U4 pk;
        pk.x = f2bf(acc[rt][nt][0]); pk.y = f2bf(acc[rt][nt][1]);
        pk.z = f2bf(acc[rt][nt][2]); pk.w = f2bf(acc[rt][nt][3]);
        *(U4*)(vT + ((size_t)batch * 768 + col) * 4096 + s) = pk;
      }
    }
  } else {
    u16* dst = (z == 0) ? qo : ko;
    float scl = (z == 0) ? QSCALE : 1.0f;
#pragma unroll
    for (int rt = 0; rt < 4; rt++)
#pragma unroll
      for (int nt = 0; nt < 4; nt++) {
        int col = n0 + wn * 64 + nt * 16 + l15;
#pragma unroll
        for (int j = 0; j < 4; j++) {
          int m = m0 + wm * 64 + rt * 16 + lg4 * 4 + j;
          dst[(size_t)m * 768 + col] = f2bf(acc[rt][nt][j] * scl);
        }
      }
  }
}

// ---------------- flash attention, BQ=32, KBLK=32, 4 waves ----------------
// waves: rg = w>>1 (q-rows 16*rg..), cg = w&1 (k-cols 16*cg..) for QK^T;
// PV: wave w owns output cols [w*192, w*192+192).
__global__ __launch_bounds__(256, 2) void attn_kernel(
    const u16* __restrict__ qg, const u16* __restrict__ kg, const u16* __restrict__ vg,
    float* __restrict__ out, u32* __restrict__ counter) {
  __shared__ char Plds[2048];               // P[32 rows][32 keys] bf16, swizzled
  __shared__ float pm[2][2][16];
  __shared__ float ps[2][2][16];
  __shared__ float mrun[32], lrun[32], alpha_s[32];
  __shared__ u32 s_task;

  const int tid = threadIdx.x;
  const int lane = tid & 63;
  const int wv = tid >> 6;
  const int rg = wv >> 1, cg = wv & 1;
  const int l15 = lane & 15, lg4 = lane >> 4;

  for (;;) {
    if (tid == 0) s_task = atomicAdd(counter, 1u);
    __syncthreads();
    u32 t = s_task;
    __syncthreads();
    if (t >= 512u) break;
    // complementary pairing: tickets i and i+256 have work summing to a constant
    int qb_i, batch;
    if (t < 256u) { qb_i = 127 - (int)(t >> 1); batch = (int)(t & 1u); }
    else          { u32 u = t - 256u; qb_i = (int)(u >> 1); batch = 2 + (int)(u & 1u); }
    const int qbase = qb_i * 32;
    const size_t boff = (size_t)batch * 4096;

    if (tid < 32) { mrun[tid] = -INFINITY; lrun[tid] = 0.f; }

    f32x4 acc_o[2][12];
#pragma unroll
    for (int rt = 0; rt < 2; rt++)
#pragma unroll
      for (int ct = 0; ct < 12; ct++) acc_o[rt][ct] = f32x4{0.f, 0.f, 0.f, 0.f};

    // Q fragments in registers: rows qbase + rg*16 + l15, full D=768 (24 k-slices)
    bf8 qf[24];
    {
      const u16* qrow = qg + (boff + qbase + rg * 16 + l15) * 768 + lg4 * 8;
#pragma unroll
      for (int tt = 0; tt < 24; tt++) qf[tt] = *(const bf8*)(const void*)(qrow + tt * 32);
    }

    const int nkt = qb_i + 1;
    for (int kt = 0; kt < nkt; kt++) {
      // ---- QK^T: S[16x16] per wave, full-D reduction, K direct from global ----
      f32x4 s0 = f32x4{0.f, 0.f, 0.f, 0.f}, s1 = f32x4{0.f, 0.f, 0.f, 0.f};
      const u16* krow = kg + (boff + kt * 32 + cg * 16 + l15) * 768 + lg4 * 8;
#pragma unroll
      for (int tt = 0; tt < 24; tt += 2) {
        bf8 ka = *(const bf8*)(const void*)(krow + tt * 32);
        bf8 kb = *(const bf8*)(const void*)(krow + tt * 32 + 32);
        s0 = mfma16(qf[tt], ka, s0);
        s1 = mfma16(qf[tt + 1], kb, s1);
      }
      f32x4 sv = s0 + s1;
      // causal mask (only diagonal tile can mask)
      if (kt == qb_i) {
#pragma unroll
        for (int j = 0; j < 4; j++) {
          int row = qbase + rg * 16 + lg4 * 4 + j;
          int col = kt * 32 + cg * 16 + l15;
          if (col > row) sv[j] = -INFINITY;
        }
      }
      // per-row max over 16 lanes (cols)
      float rmax[4];
#pragma unroll
      for (int j = 0; j < 4; j++) {
        float m = sv[j];
        m = fmaxf(m, __shfl_xor(m, 1));
        m = fmaxf(m, __shfl_xor(m, 2));
        m = fmaxf(m, __shfl_xor(m, 4));
        m = fmaxf(m, __shfl_xor(m, 8));
        rmax[j] = m;
      }
      if (l15 == 0) {
#pragma unroll
        for (int j = 0; j < 4; j++) pm[rg][cg][lg4 * 4 + j] = rmax[j];
      }
      __syncthreads();                       // b1: pm visible
      if (tid < 32) {
        float mo = mrun[tid];
        float mn = fmaxf(mo, fmaxf(pm[tid >> 4][0][tid & 15], pm[tid >> 4][1][tid & 15]));
        alpha_s[tid] = exp2f((mo - mn) * LOG2E);
        mrun[tid] = mn;
      }
      __syncthreads();                       // b2: mrun/alpha visible
      // p = exp(s - m), partial sums, write P (bf16, swizzled), rescale O
      float psum[4];
#pragma unroll
      for (int j = 0; j < 4; j++) {
        int r = rg * 16 + lg4 * 4 + j;
        float p = exp2f((sv[j] - mrun[r]) * LOG2E);
        u32 off = (u32)r * 64u + (u32)(cg * 16 + l15) * 2u;
        *(u16*)(Plds + swz7(off)) = f2bf(p);
        float su = p;
        su += __shfl_xor(su, 1);
        su += __shfl_xor(su, 2);
        su += __shfl_xor(su, 4);
        su += __shfl_xor(su, 8);
        psum[j] = su;
      }
      if (l15 == 0) {
#pragma unroll
        for (int j = 0; j < 4; j++) ps[rg][cg][lg4 * 4 + j] = psum[j];
      }
      {
        float al0[4], al1[4];
#pragma unroll
        for (int j = 0; j < 4; j++) { al0[j] = alpha_s[lg4 * 4 + j]; al1[j] = alpha_s[16 + lg4 * 4 + j]; }
#pragma unroll
        for (int ct = 0; ct < 12; ct++) {
#pragma unroll
          for (int j = 0; j < 4; j++) { acc_o[0][ct][j] *= al0[j]; acc_o[1][ct][j] *= al1[j]; }
        }
      }
      __syncthreads();                       // b3: P, ps visible
      if (tid < 32)
        lrun[tid] = lrun[tid] * alpha_s[tid] + ps[tid >> 4][0][tid & 15] + ps[tid >> 4][1][tid & 15];
      // ---- PV: O[32 x 192] += P[32x32] * V[32x192], V direct from global (vT) ----
      bf8 pa[2];
#pragma unroll
      for (int rt = 0; rt < 2; rt++) {
        u32 off = (u32)(rt * 16 + l15) * 64u + (u32)lg4 * 16u;
        pa[rt] = *(const bf8*)(const void*)(Plds + swz7(off));
      }
      const u16* vbase = vg + (size_t)batch * 3145728 + kt * 32 + lg4 * 8;
#pragma unroll
      for (int ct = 0; ct < 12; ct++) {
        int d = wv * 192 + ct * 16 + l15;
        bf8 vb = *(const bf8*)(const void*)(vbase + (size_t)d * 4096);
        acc_o[0][ct] = mfma16(pa[0], vb, acc_o[0][ct]);
        acc_o[1][ct] = mfma16(pa[1], vb, acc_o[1][ct]);
      }
    }
    // ---- epilogue: normalize and store fp32 ----
    __syncthreads();                         // lrun final
#pragma unroll
    for (int rt = 0; rt < 2; rt++) {
      float inv[4];
#pragma unroll
      for (int j = 0; j < 4; j++) inv[j] = 1.f / lrun[rt * 16 + lg4 * 4 + j];
#pragma unroll
      for (int ct = 0; ct < 12; ct++) {
#pragma unroll
        for (int j = 0; j < 4; j++) {
          size_t o = (boff + (size_t)(qbase + rt * 16 + lg4 * 4 + j)) * 768 + wv * 192 + ct * 16 + l15;
          out[o] = acc_o[rt][ct][j] * inv[j];
        }
      }
    }
  }
}

extern "C" void kernel_launch(void* const* d_in, const int* in_sizes, int n_in,
                              void* d_out, int out_size, void* d_ws, size_t ws_size,
                              hipStream_t stream) {
  const float* x  = (const float*)d_in[0];
  const float* Wq = (const float*)d_in[1];
  const float* Wk = (const float*)d_in[2];
  const float* Wv = (const float*)d_in[3];
  float* out = (float*)d_out;

  char* ws = (char*)d_ws;
  u32* counter = (u32*)ws;
  u16* xb = (u16*)(ws + 256);
  u16* qb = xb + 12582912;
  u16* kb = qb + 12582912;
  u16* vT = kb + 12582912;
  u16* wt = vT + 12582912;     // 3 x 589824

  hipMemsetAsync(d_ws, 0, 256, stream);
  cvt_x_kernel<<<12288, 256, 0, stream>>>(x, xb);
  cvt_w_kernel<<<dim3(24, 24, 3), 256, 0, stream>>>(Wq, Wk, Wv, wt);
  gemm_qkv_kernel<<<dim3(128, 6, 3), 256, 0, stream>>>(xb, wt, qb, kb, vT);
  attn_kernel<<<512, 256, 0, stream>>>(qb, kb, vT, out, counter);
}

// Round 2
// 958.667 us; speedup vs baseline: 1.3052x; 1.3052x over previous
//
#include <hip/hip_runtime.h>
#include <math.h>

// CausalAttention: B=4, S=4096, DIN=DOUT=768, fp32 in/out, bf16 MFMA compute.
// ws layout: [0,256) unused | xb bf16 | q bf16 (pre-scaled) | k bf16 |
//            vT bf16 [b][d][s] | Wt bf16 (3x transposed W)

typedef unsigned short u16;
typedef unsigned int u32;
typedef __attribute__((ext_vector_type(8))) __bf16 bf8;
typedef __attribute__((ext_vector_type(4))) float f32x4;

struct __align__(8) U4 { u16 x, y, z, w; };

#define LOG2E 1.4426950408889634f
#define QSCALE 0.03608439182435161f   // 1/sqrt(768)

__device__ __forceinline__ u16 f2bf(float f) {
  u32 u = __builtin_bit_cast(u32, f);
  u += 0x7FFFu + ((u >> 16) & 1u);      // RNE
  return (u16)(u >> 16);
}
__device__ __forceinline__ f32x4 mfma16(bf8 a, bf8 b, f32x4 c) {
  return __builtin_amdgcn_mfma_f32_16x16x32_bf16(a, b, c, 0, 0, 0);
}
__device__ __forceinline__ void stage16(const void* g, void* l) {
  __builtin_amdgcn_global_load_lds((const __attribute__((address_space(1))) void*)g,
                                   (__attribute__((address_space(3))) void*)l, 16, 0, 0);
}
// XOR swizzle, involution: key from bits >=7, modifies bits 4-6 (16B granules)
__device__ __forceinline__ u32 swz7(u32 off) { return off ^ (((off >> 7) & 7u) << 4); }

// ---------------- convert x (fp32 -> bf16), vectorized ----------------
__global__ void cvt_x_kernel(const float* __restrict__ x, u16* __restrict__ xb) {
  int i = blockIdx.x * 256 + threadIdx.x;          // float4 index, exact grid
  float4 v = ((const float4*)x)[i];
  U4 o; o.x = f2bf(v.x); o.y = f2bf(v.y); o.z = f2bf(v.z); o.w = f2bf(v.w);
  ((U4*)xb)[i] = o;
}

// ---------------- convert + transpose W: Wt[z][n][k] = bf16(W_z[k][n]) ----------------
__global__ void cvt_w_kernel(const float* __restrict__ Wq, const float* __restrict__ Wk,
                             const float* __restrict__ Wv, u16* __restrict__ wt) {
  __shared__ float tile[32][33];
  int z = blockIdx.z;
  const float* W = (z == 0) ? Wq : ((z == 1) ? Wk : Wv);
  u16* o = wt + (size_t)z * 589824;
  int n0 = blockIdx.x * 32, k0 = blockIdx.y * 32;
  int c = threadIdx.x & 31, r0 = threadIdx.x >> 5;   // 8 rows/pass
#pragma unroll
  for (int p = 0; p < 4; p++) tile[r0 + p * 8][c] = W[(size_t)(k0 + r0 + p * 8) * 768 + n0 + c];
  __syncthreads();
#pragma unroll
  for (int p = 0; p < 4; p++) o[(size_t)(n0 + r0 + p * 8) * 768 + k0 + c] = f2bf(tile[c][r0 + p * 8]);
}

// ---------------- QKV GEMM: C[16384x768] = xb * W_z, 128x128 tile, BK=64 ----------------
// z=0 -> q (scaled), z=1 -> k, z=2 -> v transposed [b][d][s]
__global__ __launch_bounds__(256) void gemm_qkv_kernel(
    const u16* __restrict__ xb, const u16* __restrict__ wt,
    u16* __restrict__ qo, u16* __restrict__ ko, u16* __restrict__ vT) {
  __shared__ char lA[16384];
  __shared__ char lB[16384];
  const int tid = threadIdx.x;
  const int lane = tid & 63, wvid = tid >> 6;
  const int wm = wvid >> 1, wn = wvid & 1;
  const int l15 = lane & 15, lg4 = lane >> 4;
  const int m0 = blockIdx.x * 128;
  const int n0 = blockIdx.y * 128;
  const int z = blockIdx.z;
  const u16* wz = wt + (size_t)z * 589824;

  f32x4 acc[4][4];
#pragma unroll
  for (int rt = 0; rt < 4; rt++)
#pragma unroll
    for (int nt = 0; nt < 4; nt++) acc[rt][nt] = f32x4{0.f, 0.f, 0.f, 0.f};

  for (int kt = 0; kt < 12; kt++) {
#pragma unroll
    for (int i = 0; i < 4; i++) {
      u32 o = (u32)i * 4096u + (u32)wvid * 1024u + (u32)lane * 16u;
      u32 lg = swz7(o);
      u32 row = lg >> 7, kbyt = lg & 127u;
      stage16((const char*)xb + ((size_t)(m0 + row) * 1536 + (size_t)kt * 128 + kbyt),
              lA + (size_t)i * 4096 + (size_t)wvid * 1024);
      stage16((const char*)wz + ((size_t)(n0 + row) * 1536 + (size_t)kt * 128 + kbyt),
              lB + (size_t)i * 4096 + (size_t)wvid * 1024);
    }
    __syncthreads();
#pragma unroll
    for (int kk = 0; kk < 2; kk++) {
      bf8 af[4], bfr[4];
#pragma unroll
      for (int rt = 0; rt < 4; rt++) {
        u32 off = (u32)(wm * 64 + rt * 16 + l15) * 128u + (u32)kk * 64u + (u32)lg4 * 16u;
        af[rt] = *(const bf8*)(const void*)(lA + swz7(off));
      }
#pragma unroll
      for (int nt = 0; nt < 4; nt++) {
        u32 off = (u32)(wn * 64 + nt * 16 + l15) * 128u + (u32)kk * 64u + (u32)lg4 * 16u;
        bfr[nt] = *(const bf8*)(const void*)(lB + swz7(off));
      }
#pragma unroll
      for (int rt = 0; rt < 4; rt++)
#pragma unroll
        for (int nt = 0; nt < 4; nt++) acc[rt][nt] = mfma16(af[rt], bfr[nt], acc[rt][nt]);
    }
    __syncthreads();
  }
  if (z == 2) {
#pragma unroll
    for (int rt = 0; rt < 4; rt++) {
      int m = m0 + wm * 64 + rt * 16 + lg4 * 4;
      int batch = m >> 12;
      int s = m & 4095;
#pragma unroll
      for (int nt = 0; nt < 4; nt++) {
        int col = n0 + wn * 64 + nt * 16 + l15;
        U4 pk;
        pk.x = f2bf(acc[rt][nt][0]); pk.y = f2bf(acc[rt][nt][1]);
        pk.z = f2bf(acc[rt][nt][2]); pk.w = f2bf(acc[rt][nt][3]);
        *(U4*)(vT + ((size_t)batch * 768 + col) * 4096 + s) = pk;
      }
    }
  } else {
    u16* dst = (z == 0) ? qo : ko;
    float scl = (z == 0) ? QSCALE : 1.0f;
#pragma unroll
    for (int rt = 0; rt < 4; rt++)
#pragma unroll
      for (int nt = 0; nt < 4; nt++) {
        int col = n0 + wn * 64 + nt * 16 + l15;
#pragma unroll
        for (int j = 0; j < 4; j++) {
          int m = m0 + wm * 64 + rt * 16 + lg4 * 4 + j;
          dst[(size_t)m * 768 + col] = f2bf(acc[rt][nt][j] * scl);
        }
      }
  }
}

// ---------------- flash attention v2: 8 waves, BQ=32, KBLK=128 ----------------
// QK^T: rg=wv>>2 picks 16 q-rows, cg=wv&3 picks 32 keys (2 col-tiles).
// PV:   wave wv owns output cols [wv*96, wv*96+96).
// Q in LDS subtiled [24 kslices][32 rows][64B], slot-permuted (conflict-free).
// P in LDS [32 rows][256B], XOR-swizzled by (row&7)<<4 on byte offset.
__global__ __launch_bounds__(512, 4) void attn_kernel(
    const u16* __restrict__ qg, const u16* __restrict__ kg, const u16* __restrict__ vg,
    float* __restrict__ out) {
  __shared__ char Qlds[49152];
  __shared__ char Plds[8192];
  __shared__ float pm[2][4][16];
  __shared__ float ps[2][4][16];
  __shared__ float mrun[32], lrun[32], alpha_s[32];

  const int tid = threadIdx.x;
  const int lane = tid & 63;
  const int wv = tid >> 6;           // 0..7
  const int rg = wv >> 2;            // 0..1
  const int cg = wv & 3;             // 0..3
  const int l15 = lane & 15, lg4 = lane >> 4;

  const int t = blockIdx.x;
  const int qb_i = 127 - (t >> 2);   // big tasks dispatched first
  const int batch = t & 3;
  const int qbase = qb_i * 32;
  const size_t boff = (size_t)batch * 4096;
  const int nt = (qbase + 32 + 127) >> 7;

  // ---- stage Q tile (32 x 768 bf16) into subtiled LDS ----
#pragma unroll
  for (int j = 0; j < 6; j++) {
    int li = j * 512 + tid;                    // 16B-chunk id, 0..3071
    int row = li / 96;
    int c16 = li - row * 96;                   // 0..95
    int tt = c16 >> 2, sl = c16 & 3;
    u32 daddr = (u32)tt * 2048u + (u32)row * 64u + (u32)((sl ^ ((row >> 1) & 3)) << 4);
    bf8 v = *(const bf8*)(const void*)(qg + (boff + qbase + row) * 768 + c16 * 8);
    *(bf8*)(void*)(Qlds + daddr) = v;
  }
  if (tid < 32) { mrun[tid] = -INFINITY; lrun[tid] = 0.f; }
  __syncthreads();

  // per-lane constants
  const int qrow_loc = rg * 16 + l15;
  const u32 qlds_base = (u32)qrow_loc * 64u + (u32)((lg4 ^ ((qrow_loc >> 1) & 3)) << 4);
  const u16* krp0 = kg + (boff + cg * 32 + l15) * 768 + lg4 * 8;
  const u16* krp1 = krp0 + (size_t)16 * 768;
  const u16* vrp = vg + ((size_t)batch * 768 + wv * 96 + l15) * 4096 + lg4 * 8;
  const u32 pa_col = ((u32)lg4 * 16u) ^ ((u32)(l15 & 3) << 4);   // bits 4-5 of swizzle
  const u32 pa_kx = (u32)((l15 >> 2) & 1);                       // bit 6 of swizzle

  f32x4 acc[2][6];
#pragma unroll
  for (int rt = 0; rt < 2; rt++)
#pragma unroll
    for (int ct = 0; ct < 6; ct++) acc[rt][ct] = f32x4{0.f, 0.f, 0.f, 0.f};

  for (int kt = 0; kt < nt; kt++) {
    const int kb = kt * 128;
    // ---- QK^T: 16 rows x 32 cols per wave, 4 chains ----
    f32x4 s00 = f32x4{0.f,0.f,0.f,0.f}, s01 = s00, s10 = s00, s11 = s00;
    const u16* ka = krp0 + (size_t)kb * 768;
    const u16* kbp = krp1 + (size_t)kb * 768;
#pragma unroll
    for (int tt = 0; tt < 24; tt += 2) {
      bf8 qa0 = *(const bf8*)(const void*)(Qlds + qlds_base + tt * 2048);
      bf8 qa1 = *(const bf8*)(const void*)(Qlds + qlds_base + (tt + 1) * 2048);
      bf8 k00 = *(const bf8*)(const void*)(ka + tt * 32);
      bf8 k01 = *(const bf8*)(const void*)(ka + tt * 32 + 32);
      bf8 k10 = *(const bf8*)(const void*)(kbp + tt * 32);
      bf8 k11 = *(const bf8*)(const void*)(kbp + tt * 32 + 32);
      s00 = mfma16(qa0, k00, s00);
      s10 = mfma16(qa0, k10, s10);
      s01 = mfma16(qa1, k01, s01);
      s11 = mfma16(qa1, k11, s11);
    }
    f32x4 sv0 = s00 + s01;      // cols kb + cg*32 + l15
    f32x4 sv1 = s10 + s11;      // cols kb + cg*32 + 16 + l15

    if (kt == nt - 1) {         // only the last tile can cross the diagonal
      int col0 = kb + cg * 32 + l15;
      int rowg = qbase + rg * 16 + lg4 * 4;
#pragma unroll
      for (int j = 0; j < 4; j++) {
        if (col0 > rowg + j) sv0[j] = -INFINITY;
        if (col0 + 16 > rowg + j) sv1[j] = -INFINITY;
      }
    }
    // per-row max over this wave's 32 cols
    float rmax[4];
#pragma unroll
    for (int j = 0; j < 4; j++) {
      float m = fmaxf(sv0[j], sv1[j]);
      m = fmaxf(m, __shfl_xor(m, 1));
      m = fmaxf(m, __shfl_xor(m, 2));
      m = fmaxf(m, __shfl_xor(m, 4));
      m = fmaxf(m, __shfl_xor(m, 8));
      rmax[j] = m;
    }
    if (l15 == 0) {
#pragma unroll
      for (int j = 0; j < 4; j++) pm[rg][cg][lg4 * 4 + j] = rmax[j];
    }
    __syncthreads();                     // b1
    if (tid < 32) {
      int r2 = tid >> 4, ix = tid & 15;
      float mo = mrun[tid];
      float mn = fmaxf(fmaxf(pm[r2][0][ix], pm[r2][1][ix]), fmaxf(pm[r2][2][ix], pm[r2][3][ix]));
      mn = fmaxf(mo, mn);
      alpha_s[tid] = exp2f((mo - mn) * LOG2E);
      mrun[tid] = mn;
    }
    __syncthreads();                     // b2
    // p = exp(s - m), write P (bf16, swizzled), partial row sums
    float psum[4];
    const int prow0 = rg * 16 + lg4 * 4;
#pragma unroll
    for (int j = 0; j < 4; j++) {
      int r = prow0 + j;
      float mrow = mrun[r];
      float p0 = exp2f((sv0[j] - mrow) * LOG2E);
      float p1 = exp2f((sv1[j] - mrow) * LOG2E);
      u32 rb = (u32)r * 256u;
      u32 msk = (u32)(r & 7) << 4;
      *(u16*)(void*)(Plds + rb + (((u32)(cg * 32 + l15) * 2u) ^ msk)) = f2bf(p0);
      *(u16*)(void*)(Plds + rb + (((u32)(cg * 32 + 16 + l15) * 2u) ^ msk)) = f2bf(p1);
      float su = p0 + p1;
      su += __shfl_xor(su, 1);
      su += __shfl_xor(su, 2);
      su += __shfl_xor(su, 4);
      su += __shfl_xor(su, 8);
      psum[j] = su;
    }
    if (l15 == 0) {
#pragma unroll
      for (int j = 0; j < 4; j++) ps[rg][cg][lg4 * 4 + j] = psum[j];
    }
    // rescale O accumulators
    {
      float al[8];
#pragma unroll
      for (int rt = 0; rt < 2; rt++)
#pragma unroll
        for (int j = 0; j < 4; j++) al[rt * 4 + j] = alpha_s[rt * 16 + lg4 * 4 + j];
#pragma unroll
      for (int ct = 0; ct < 6; ct++)
#pragma unroll
        for (int rt = 0; rt < 2; rt++)
#pragma unroll
          for (int j = 0; j < 4; j++) acc[rt][ct][j] *= al[rt * 4 + j];
    }
    __syncthreads();                     // b3: P + ps visible
    if (tid < 32) {
      int r2 = tid >> 4, ix = tid & 15;
      lrun[tid] = lrun[tid] * alpha_s[tid] +
                  ps[r2][0][ix] + ps[r2][1][ix] + ps[r2][2][ix] + ps[r2][3][ix];
    }
    // ---- PV: O[32 x 96] += P[32x128] * V[128x96] per wave ----
    const u16* vb_base = vrp + kb;
#pragma unroll
    for (int ks = 0; ks < 4; ks++) {
      u32 kss = ((u32)ks ^ pa_kx) * 64u;
      bf8 pa0 = *(const bf8*)(const void*)(Plds + (u32)l15 * 256u + pa_col + kss);
      bf8 pa1 = *(const bf8*)(const void*)(Plds + ((u32)l15 * 256u + 4096u) + pa_col + kss);
#pragma unroll
      for (int ct = 0; ct < 6; ct++) {
        bf8 vb = *(const bf8*)(const void*)(vb_base + (size_t)ct * 16 * 4096 + ks * 32);
        acc[0][ct] = mfma16(pa0, vb, acc[0][ct]);
        acc[1][ct] = mfma16(pa1, vb, acc[1][ct]);
      }
    }
  }
  __syncthreads();
  // ---- epilogue: normalize and store fp32 ----
  float inv[8];
#pragma unroll
  for (int rt = 0; rt < 2; rt++)
#pragma unroll
    for (int j = 0; j < 4; j++) inv[rt * 4 + j] = 1.f / lrun[rt * 16 + lg4 * 4 + j];
#pragma unroll
  for (int ct = 0; ct < 6; ct++)
#pragma unroll
    for (int rt = 0; rt < 2; rt++)
#pragma unroll
      for (int j = 0; j < 4; j++) {
        size_t o = (boff + (size_t)(qbase + rt * 16 + lg4 * 4 + j)) * 768 + wv * 96 + ct * 16 + l15;
        out[o] = acc[rt][ct][j] * inv[rt * 4 + j];
      }
}

extern "C" void kernel_launch(void* const* d_in, const int* in_sizes, int n_in,
                              void* d_out, int out_size, void* d_ws, size_t ws_size,
                              hipStream_t stream) {
  const float* x  = (const float*)d_in[0];
  const float* Wq = (const float*)d_in[1];
  const float* Wk = (const float*)d_in[2];
  const float* Wv = (const float*)d_in[3];
  float* out = (float*)d_out;

  char* ws = (char*)d_ws;
  u16* xb = (u16*)(ws + 256);
  u16* qb = xb + 12582912;
  u16* kb = qb + 12582912;
  u16* vT = kb + 12582912;
  u16* wt = vT + 12582912;     // 3 x 589824

  cvt_x_kernel<<<12288, 256, 0, stream>>>(x, xb);
  cvt_w_kernel<<<dim3(24, 24, 3), 256, 0, stream>>>(Wq, Wk, Wv, wt);
  gemm_qkv_kernel<<<dim3(128, 6, 3), 256, 0, stream>>>(xb, wt, qb, kb, vT);
  attn_kernel<<<512, 512, 0, stream>>>(qb, kb, vT, out);
}